// Round 1
// baseline (832.354 us; speedup 1.0000x reference)
//
#include <hip/hip_runtime.h>
#include <math.h>

// ---------------------------------------------------------------------------
// HybridBinaryClassifier: conv1(5x5,s2,p1)+relu -> pool(2x2,s1) ->
// conv2(3x3,s2,p1)+relu -> pool(2x2,s1) -> fc1(relu) -> fc2 -> head -> graph
// All fp32. B=256.
// ---------------------------------------------------------------------------

// conv1: x[256,3,250,250] -> relu(conv+b) -> h1[256,6,124,124]
// thread: one (b, oh), 4 consecutive ow, all 6 oc.  31 groups * 124 oh * 256 b
__global__ __launch_bounds__(256) void k_conv1(const float* __restrict__ x,
                                               const float* __restrict__ w,
                                               const float* __restrict__ bias,
                                               float* __restrict__ out) {
    int idx = blockIdx.x * 256 + threadIdx.x;   // exactly 984064
    int g   = idx % 31;
    int t   = idx / 31;
    int oh  = t % 124;
    int b   = t / 124;
    int ow0 = g * 4;
    int c0  = ow0 * 2 - 1;

    float acc[6][4];
#pragma unroll
    for (int oc = 0; oc < 6; ++oc)
#pragma unroll
        for (int j = 0; j < 4; ++j) acc[oc][j] = 0.f;

    const float* xb = x + (size_t)b * 3 * 250 * 250;

#pragma unroll 1
    for (int ci = 0; ci < 3; ++ci) {
#pragma unroll
        for (int kh = 0; kh < 5; ++kh) {
            int ih = oh * 2 - 1 + kh;
            if (ih < 0 || ih >= 250) continue;
            const float* row = xb + (size_t)(ci * 250 + ih) * 250;
            float r[11];
#pragma unroll
            for (int u = 0; u < 11; ++u) {
                int c = c0 + u;
                r[u] = (c >= 0 && c < 250) ? row[c] : 0.f;
            }
#pragma unroll
            for (int oc = 0; oc < 6; ++oc) {
                const float* wp = w + (oc * 3 + ci) * 25 + kh * 5;
#pragma unroll
                for (int kw = 0; kw < 5; ++kw) {
                    float wv = wp[kw];
#pragma unroll
                    for (int j = 0; j < 4; ++j)
                        acc[oc][j] = fmaf(r[2 * j + kw], wv, acc[oc][j]);
                }
            }
        }
    }
#pragma unroll
    for (int oc = 0; oc < 6; ++oc) {
        float4 st;
        st.x = fmaxf(acc[oc][0] + bias[oc], 0.f);
        st.y = fmaxf(acc[oc][1] + bias[oc], 0.f);
        st.z = fmaxf(acc[oc][2] + bias[oc], 0.f);
        st.w = fmaxf(acc[oc][3] + bias[oc], 0.f);
        *(float4*)(out + ((((size_t)b * 6 + oc) * 124 + oh) * 124 + ow0)) = st;
    }
}

// generic 2x2 stride-1 maxpool on square planes
__global__ __launch_bounds__(256) void k_pool(const float* __restrict__ in,
                                              float* __restrict__ out,
                                              int wout, int win, int n) {
    int idx = blockIdx.x * 256 + threadIdx.x;
    if (idx >= n) return;
    int pw = idx % wout;
    int t  = idx / wout;
    int ph = t % wout;
    int bc = t / wout;
    const float* p = in + (size_t)bc * win * win + ph * win + pw;
    float m0 = fmaxf(p[0], p[1]);
    float m1 = fmaxf(p[win], p[win + 1]);
    out[idx] = fmaxf(m0, m1);
}

// conv2: p1[256,6,123,123] -> relu(conv+b) -> h2[256,15,62,62]
__global__ __launch_bounds__(256) void k_conv2(const float* __restrict__ in,
                                               const float* __restrict__ w,
                                               const float* __restrict__ bias,
                                               float* __restrict__ out) {
    int idx = blockIdx.x * 256 + threadIdx.x;   // exactly 253952
    int g   = idx & 15;
    int t   = idx >> 4;
    int oh  = t % 62;
    int b   = t / 62;
    int ow0 = g * 4;
    int c0  = ow0 * 2 - 1;

    float acc[15][4];
#pragma unroll
    for (int oc = 0; oc < 15; ++oc)
#pragma unroll
        for (int j = 0; j < 4; ++j) acc[oc][j] = 0.f;

    const float* ib = in + (size_t)b * 6 * 123 * 123;

#pragma unroll 1
    for (int ci = 0; ci < 6; ++ci) {
#pragma unroll
        for (int kh = 0; kh < 3; ++kh) {
            int ih = oh * 2 - 1 + kh;
            if (ih < 0 || ih >= 123) continue;
            const float* row = ib + (size_t)(ci * 123 + ih) * 123;
            float r[9];
#pragma unroll
            for (int u = 0; u < 9; ++u) {
                int c = c0 + u;
                r[u] = (c >= 0 && c < 123) ? row[c] : 0.f;
            }
#pragma unroll
            for (int oc = 0; oc < 15; ++oc) {
                const float* wp = w + (oc * 6 + ci) * 9 + kh * 3;
#pragma unroll
                for (int kw = 0; kw < 3; ++kw) {
                    float wv = wp[kw];
#pragma unroll
                    for (int j = 0; j < 4; ++j)
                        acc[oc][j] = fmaf(r[2 * j + kw], wv, acc[oc][j]);
                }
            }
        }
    }
#pragma unroll
    for (int oc = 0; oc < 15; ++oc) {
#pragma unroll
        for (int j = 0; j < 4; ++j) {
            int ow = ow0 + j;
            if (ow < 62)
                out[(((size_t)b * 15 + oc) * 62 + oh) * 62 + ow] =
                    fmaxf(acc[oc][j] + bias[oc], 0.f);
        }
    }
}

// fc1: A=p2 [256][55815] row-major, B=fc1_w [120][55815].
// Split-K GEMM: block tile 128m x 128n(120 valid) x 60k, thread 8x8 micro-tile
// (interleaved +16 mapping, LDS stride 61 -> conflict-free b32 reads).
// grid (128 kb, 2 mt); partial[kb][256][120] summed by k_fc1red.
__global__ __launch_bounds__(256) void k_fc1(const float* __restrict__ A,
                                             const float* __restrict__ B,
                                             float* __restrict__ partial) {
    __shared__ float As[128][61];
    __shared__ float Bs[128][61];
    const int K = 55815;
    int tid = threadIdx.x;
    int kb  = blockIdx.x;          // 0..127
    int m0  = blockIdx.y * 128;    // 0 or 128
    int mx  = tid >> 4;            // 0..15
    int nx  = tid & 15;            // 0..15

    float acc[8][8];
#pragma unroll
    for (int i = 0; i < 8; ++i)
#pragma unroll
        for (int j = 0; j < 8; ++j) acc[i][j] = 0.f;

    for (int ch = kb; ch < 931; ch += 128) {   // 931 = ceil(55815/60)
        int k0 = ch * 60;
#pragma unroll 1
        for (int it = 0; it < 30; ++it) {
            int li  = it * 256 + tid;          // < 7680
            int row = li / 60;
            int col = li - row * 60;
            int k   = k0 + col;
            float av = 0.f, bv = 0.f;
            if (k < K) {
                av = A[(size_t)(m0 + row) * K + k];
                if (row < 120) bv = B[(size_t)row * K + k];
            }
            As[row][col] = av;
            Bs[row][col] = bv;
        }
        __syncthreads();
#pragma unroll 4
        for (int k = 0; k < 60; ++k) {
            float a[8], b[8];
#pragma unroll
            for (int i = 0; i < 8; ++i) a[i] = As[mx + 16 * i][k];
#pragma unroll
            for (int j = 0; j < 8; ++j) b[j] = Bs[nx + 16 * j][k];
#pragma unroll
            for (int i = 0; i < 8; ++i)
#pragma unroll
                for (int j = 0; j < 8; ++j)
                    acc[i][j] = fmaf(a[i], b[j], acc[i][j]);
        }
        __syncthreads();
    }

    float* pp = partial + (size_t)kb * 256 * 120;
#pragma unroll
    for (int i = 0; i < 8; ++i) {
        int m = m0 + mx + 16 * i;
#pragma unroll
        for (int j = 0; j < 8; ++j) {
            int n = nx + 16 * j;
            if (n < 120) pp[m * 120 + n] = acc[i][j];
        }
    }
}

// reduce partials + bias + relu -> fc1out[256][120]
__global__ __launch_bounds__(256) void k_fc1red(const float* __restrict__ partial,
                                                const float* __restrict__ bias,
                                                float* __restrict__ out) {
    int idx = blockIdx.x * 256 + threadIdx.x;   // 30720
    int n = idx % 120;
    float s = bias[n];
#pragma unroll 8
    for (int kb = 0; kb < 128; ++kb) s += partial[(size_t)kb * 30720 + idx];
    out[idx] = fmaxf(s, 0.f);
}

// fc2: features[256][84] = fc1out[256][120] @ w[84][120]^T + b
__global__ __launch_bounds__(256) void k_fc2(const float* __restrict__ h,
                                             const float* __restrict__ w,
                                             const float* __restrict__ bias,
                                             float* __restrict__ out) {
    int idx = blockIdx.x * 256 + threadIdx.x;   // 21504
    int n = idx % 84;
    int m = idx / 84;
    const float* hp = h + m * 120;
    const float* wp = w + n * 120;
    float s = bias[n];
#pragma unroll 4
    for (int k = 0; k < 120; ++k) s = fmaf(hp[k], wp[k], s);
    out[idx] = s;
}

// head: fc3 -> tanh-param layer -> sigmoid; also row norms of features
__global__ __launch_bounds__(256) void k_head(const float* __restrict__ f,
                                              const float* __restrict__ w3,
                                              const float* __restrict__ b3,
                                              const float* __restrict__ plw,
                                              const float* __restrict__ plb,
                                              const float* __restrict__ pls,
                                              const float* __restrict__ plbias,
                                              float* __restrict__ probs,
                                              float* __restrict__ norms) {
    int b = threadIdx.x;            // 0..255, single block
    const float* fp = f + b * 84;
    float nsq = 0.f, lg = b3[0];
#pragma unroll 4
    for (int k = 0; k < 84; ++k) {
        float v = fp[k];
        nsq = fmaf(v, v, nsq);
        lg  = fmaf(v, w3[k], lg);
    }
    float z = tanhf(lg * plw[0] + plb[0]) * pls[0] + plbias[0];
    probs[b] = 1.f / (1.f + expf(-z));
    norms[b] = sqrtf(nsq);
}

// graph: block i computes cosine-sim row i, adjacency, degree-weighted agg
__global__ __launch_bounds__(256) void k_graph(const float* __restrict__ f,
                                               const float* __restrict__ probs,
                                               const float* __restrict__ norms,
                                               float* __restrict__ out) {
    __shared__ float fi[84];
    __shared__ float sd[4], sv[4];
    int i = blockIdx.x;
    int j = threadIdx.x;
    if (j < 84) fi[j] = f[i * 84 + j];
    __syncthreads();
    const float* fj = f + j * 84;
    float dot = 0.f;
#pragma unroll 4
    for (int k = 0; k < 84; ++k) dot = fmaf(fi[k], fj[k], dot);
    float sim = dot / (norms[i] * norms[j] + 1e-12f);
    bool adj = (j != i) && (sim >= 0.0f);
    float d = adj ? 1.f : 0.f;
    float v = adj ? probs[j] : 0.f;
#pragma unroll
    for (int off = 32; off >= 1; off >>= 1) {
        d += __shfl_down(d, off);
        v += __shfl_down(v, off);
    }
    int wave = j >> 6, lane = j & 63;
    if (lane == 0) { sd[wave] = d; sv[wave] = v; }
    __syncthreads();
    if (j == 0) {
        float D = sd[0] + sd[1] + sd[2] + sd[3];
        float V = sv[0] + sv[1] + sv[2] + sv[3];
        float nm = (D > 0.f) ? (V / fmaxf(D, 1.f)) : 0.f;
        float agg = (probs[i] + nm) / (1.f + D);
        out[2 * i]     = agg;
        out[2 * i + 1] = 1.f - agg;
    }
}

extern "C" void kernel_launch(void* const* d_in, const int* in_sizes, int n_in,
                              void* d_out, int out_size, void* d_ws, size_t ws_size,
                              hipStream_t stream) {
    const float* x    = (const float*)d_in[0];
    const float* w1   = (const float*)d_in[1];
    const float* b1   = (const float*)d_in[2];
    const float* w2   = (const float*)d_in[3];
    const float* b2   = (const float*)d_in[4];
    const float* fw1  = (const float*)d_in[5];
    const float* fb1  = (const float*)d_in[6];
    const float* fw2  = (const float*)d_in[7];
    const float* fb2  = (const float*)d_in[8];
    const float* fw3  = (const float*)d_in[9];
    const float* fb3  = (const float*)d_in[10];
    const float* plw  = (const float*)d_in[11];
    const float* plb  = (const float*)d_in[12];
    const float* pls  = (const float*)d_in[13];
    const float* plbi = (const float*)d_in[14];
    float* out = (float*)d_out;

    float* ws = (float*)d_ws;
    // region A: h1 (23,617,536 f) later reused for h2 (14,753,280 f)
    float* h1 = ws;
    float* h2 = ws;
    // region B: p1 (23,238,144 f) later reused for p2 (14,288,640 f)
    float* p1 = ws + 23617536;
    float* p2 = p1;
    float* partial  = ws + 23617536 + 23238144;   // 3,932,160 f
    float* fc1out   = partial + 3932160;          // 30,720 f
    float* features = fc1out + 30720;             // 21,504 f
    float* probs    = features + 21504;           // 256 f
    float* norms    = probs + 256;                // 256 f

    k_conv1<<<3844, 256, 0, stream>>>(x, w1, b1, h1);
    k_pool<<<90774, 256, 0, stream>>>(h1, p1, 123, 124, 23238144);
    k_conv2<<<992, 256, 0, stream>>>(p1, w2, b2, h2);
    k_pool<<<55815, 256, 0, stream>>>(h2, p2, 61, 62, 14288640);
    k_fc1<<<dim3(128, 2), 256, 0, stream>>>(p2, fw1, partial);
    k_fc1red<<<120, 256, 0, stream>>>(partial, fb1, fc1out);
    k_fc2<<<84, 256, 0, stream>>>(fc1out, fw2, fb2, features);
    k_head<<<1, 256, 0, stream>>>(features, fw3, fb3, plw, plb, pls, plbi,
                                  probs, norms);
    k_graph<<<256, 256, 0, stream>>>(features, probs, norms, out);
}

// Round 2
// 783.818 us; speedup vs baseline: 1.0619x; 1.0619x over previous
//
#include <hip/hip_runtime.h>
#include <math.h>

// ---------------------------------------------------------------------------
// HybridBinaryClassifier, round 2: fused conv+pool stages.
//   k_c1p1: conv1(5x5,s2,p1)+relu+pool(2x2,s1): x[256,3,250,250] -> p1[256,6,123,123]
//   k_c2p2: conv2(3x3,s2,p1)+relu+pool(2x2,s1): p1 -> p2[256,15,61,61]
// then fc1 split-K GEMM, fc2, head, graph (unchanged from round 1).
// ---------------------------------------------------------------------------

// Fused conv1+pool1. Block: one image b, one tile of PH=7 pooled rows.
// Stage input rows for one ci into LDS (coalesced), conv-accumulate in regs,
// write relu'd conv tile (8 rows x 6 oc x 124) to LDS, pool from LDS.
__global__ __launch_bounds__(256) void k_c1p1(const float* __restrict__ x,
                                              const float* __restrict__ w,
                                              const float* __restrict__ bias,
                                              float* __restrict__ p1) {
    __shared__ float xs[19][252];      // input staging, left-padded by 1 col
    __shared__ float cb[8][6][124];    // conv output tile

    const int t   = blockIdx.x;        // 0..17 row tile
    const int b   = blockIdx.y;        // 0..255
    const int tid = threadIdx.x;

    const int ph0   = 7 * t;
    const int prows = min(7, 123 - ph0);   // pooled rows this tile
    const int crows = prows + 1;           // conv rows this tile (<=8)
    const int oh0   = ph0;
    const int ihlo  = 2 * oh0 - 1;
    const int rows  = 2 * crows + 3;       // staged input rows (<=19)

    // conv work unit: (ur, g): conv row ur, 4 cols at ow0=4g, all 6 oc
    const int ur = tid / 31;
    const int g  = tid % 31;
    const bool active = (ur < crows);

    float acc[6][4];
#pragma unroll
    for (int oc = 0; oc < 6; ++oc)
#pragma unroll
        for (int j = 0; j < 4; ++j) acc[oc][j] = 0.f;

    const float* xb = x + (size_t)b * 3 * 62500;

    for (int ci = 0; ci < 3; ++ci) {
        __syncthreads();   // protect xs from previous ci's readers
        // stage rows [ihlo, ihlo+rows) of channel ci; LDS col = global col + 1
        const float* xc = xb + (size_t)ci * 62500;
        for (int s = tid; s < rows * 252; s += 256) {
            int r  = s / 252;
            int c  = s % 252;
            int gc = c - 1;
            int ih = ihlo + r;
            float v = 0.f;
            if (ih >= 0 && ih < 250 && gc >= 0 && gc < 250)
                v = xc[(size_t)ih * 250 + gc];
            xs[r][c] = v;
        }
        __syncthreads();

        if (active) {
#pragma unroll
            for (int kh = 0; kh < 5; ++kh) {
                int lr = 2 * ur + kh;
                float rr[11];
#pragma unroll
                for (int u2 = 0; u2 < 11; ++u2) rr[u2] = xs[lr][8 * g + u2];
#pragma unroll
                for (int oc = 0; oc < 6; ++oc) {
                    const float* wp = w + (oc * 3 + ci) * 25 + kh * 5;
#pragma unroll
                    for (int kw = 0; kw < 5; ++kw) {
                        float wv = wp[kw];
#pragma unroll
                        for (int j = 0; j < 4; ++j)
                            acc[oc][j] = fmaf(rr[2 * j + kw], wv, acc[oc][j]);
                    }
                }
            }
        }
    }

    __syncthreads();
    if (active) {
#pragma unroll
        for (int oc = 0; oc < 6; ++oc) {
            float bv = bias[oc];
            float4 st;
            st.x = fmaxf(acc[oc][0] + bv, 0.f);
            st.y = fmaxf(acc[oc][1] + bv, 0.f);
            st.z = fmaxf(acc[oc][2] + bv, 0.f);
            st.w = fmaxf(acc[oc][3] + bv, 0.f);
            ((float4*)&cb[ur][oc][0])[g] = st;
        }
    }
    __syncthreads();

    // pool: prows x 6 oc x 123 cols
    int npool = prows * 6 * 123;
    for (int u = tid; u < npool; u += 256) {
        int pw = u % 123;
        int t2 = u / 123;
        int oc = t2 % 6;
        int pr = t2 / 6;
        float m0 = fmaxf(cb[pr][oc][pw], cb[pr][oc][pw + 1]);
        float m1 = fmaxf(cb[pr + 1][oc][pw], cb[pr + 1][oc][pw + 1]);
        p1[(((size_t)b * 6 + oc) * 123 + (ph0 + pr)) * 123 + pw] = fmaxf(m0, m1);
    }
}

// Fused conv2+pool2. Same structure: PH=7 pooled rows/tile, 6 input channels.
// conv unit: (ur, g): conv row ur, 2 cols at ow0=2g, all 15 oc.
__global__ __launch_bounds__(256) void k_c2p2(const float* __restrict__ p1,
                                              const float* __restrict__ w,
                                              const float* __restrict__ bias,
                                              float* __restrict__ p2) {
    __shared__ float xs[17][126];      // input staging, left-padded by 1 col
    __shared__ float cb[8][15][64];    // conv output tile (62 cols used)

    const int t   = blockIdx.x;        // 0..8 row tile
    const int b   = blockIdx.y;
    const int tid = threadIdx.x;

    const int ph0   = 7 * t;
    const int prows = min(7, 61 - ph0);
    const int crows = prows + 1;       // <=8 conv rows, oh in [ph0, ph0+crows)
    const int ihlo  = 2 * ph0 - 1;
    const int rows  = 2 * crows + 1;   // staged input rows (<=17)

    const int ur = tid / 31;
    const int g  = tid % 31;
    const bool active = (ur < crows);

    float acc[15][2];
#pragma unroll
    for (int oc = 0; oc < 15; ++oc) {
        acc[oc][0] = 0.f; acc[oc][1] = 0.f;
    }

    const float* ib = p1 + (size_t)b * 6 * 15129;

    for (int ci = 0; ci < 6; ++ci) {
        __syncthreads();
        const float* xc = ib + (size_t)ci * 15129;
        for (int s = tid; s < rows * 126; s += 256) {
            int r  = s / 126;
            int c  = s % 126;
            int gc = c - 1;
            int ih = ihlo + r;
            float v = 0.f;
            if (ih >= 0 && ih < 123 && gc >= 0 && gc < 123)
                v = xc[(size_t)ih * 123 + gc];
            xs[r][c] = v;
        }
        __syncthreads();

        if (active) {
#pragma unroll
            for (int kh = 0; kh < 3; ++kh) {
                int lr = 2 * ur + kh;
                float rr[5];
#pragma unroll
                for (int u2 = 0; u2 < 5; ++u2) rr[u2] = xs[lr][4 * g + u2];
#pragma unroll
                for (int oc = 0; oc < 15; ++oc) {
                    const float* wp = w + (oc * 6 + ci) * 9 + kh * 3;
#pragma unroll
                    for (int kw = 0; kw < 3; ++kw) {
                        float wv = wp[kw];
                        acc[oc][0] = fmaf(rr[kw], wv, acc[oc][0]);
                        acc[oc][1] = fmaf(rr[kw + 2], wv, acc[oc][1]);
                    }
                }
            }
        }
    }

    __syncthreads();
    if (active) {
#pragma unroll
        for (int oc = 0; oc < 15; ++oc) {
            float bv = bias[oc];
            float2 st;
            st.x = fmaxf(acc[oc][0] + bv, 0.f);
            st.y = fmaxf(acc[oc][1] + bv, 0.f);
            ((float2*)&cb[ur][oc][0])[g] = st;
        }
    }
    __syncthreads();

    int npool = prows * 15 * 61;
    for (int u = tid; u < npool; u += 256) {
        int pw = u % 61;
        int t2 = u / 61;
        int oc = t2 % 15;
        int pr = t2 / 15;
        float m0 = fmaxf(cb[pr][oc][pw], cb[pr][oc][pw + 1]);
        float m1 = fmaxf(cb[pr + 1][oc][pw], cb[pr + 1][oc][pw + 1]);
        p2[(((size_t)b * 15 + oc) * 61 + (ph0 + pr)) * 61 + pw] = fmaxf(m0, m1);
    }
}

// fc1: A=p2 [256][55815] row-major, B=fc1_w [120][55815].
// Split-K GEMM: block tile 128m x 128n(120 valid) x 60k, thread 8x8 micro-tile
__global__ __launch_bounds__(256) void k_fc1(const float* __restrict__ A,
                                             const float* __restrict__ B,
                                             float* __restrict__ partial) {
    __shared__ float As[128][61];
    __shared__ float Bs[128][61];
    const int K = 55815;
    int tid = threadIdx.x;
    int kb  = blockIdx.x;          // 0..127
    int m0  = blockIdx.y * 128;    // 0 or 128
    int mx  = tid >> 4;            // 0..15
    int nx  = tid & 15;            // 0..15

    float acc[8][8];
#pragma unroll
    for (int i = 0; i < 8; ++i)
#pragma unroll
        for (int j = 0; j < 8; ++j) acc[i][j] = 0.f;

    for (int ch = kb; ch < 931; ch += 128) {   // 931 = ceil(55815/60)
        int k0 = ch * 60;
#pragma unroll 1
        for (int it = 0; it < 30; ++it) {
            int li  = it * 256 + tid;          // < 7680
            int row = li / 60;
            int col = li - row * 60;
            int k   = k0 + col;
            float av = 0.f, bv = 0.f;
            if (k < K) {
                av = A[(size_t)(m0 + row) * K + k];
                if (row < 120) bv = B[(size_t)row * K + k];
            }
            As[row][col] = av;
            Bs[row][col] = bv;
        }
        __syncthreads();
#pragma unroll 4
        for (int k = 0; k < 60; ++k) {
            float a[8], b[8];
#pragma unroll
            for (int i = 0; i < 8; ++i) a[i] = As[mx + 16 * i][k];
#pragma unroll
            for (int j = 0; j < 8; ++j) b[j] = Bs[nx + 16 * j][k];
#pragma unroll
            for (int i = 0; i < 8; ++i)
#pragma unroll
                for (int j = 0; j < 8; ++j)
                    acc[i][j] = fmaf(a[i], b[j], acc[i][j]);
        }
        __syncthreads();
    }

    float* pp = partial + (size_t)kb * 256 * 120;
#pragma unroll
    for (int i = 0; i < 8; ++i) {
        int m = m0 + mx + 16 * i;
#pragma unroll
        for (int j = 0; j < 8; ++j) {
            int n = nx + 16 * j;
            if (n < 120) pp[m * 120 + n] = acc[i][j];
        }
    }
}

// reduce partials + bias + relu -> fc1out[256][120]
__global__ __launch_bounds__(256) void k_fc1red(const float* __restrict__ partial,
                                                const float* __restrict__ bias,
                                                float* __restrict__ out) {
    int idx = blockIdx.x * 256 + threadIdx.x;   // 30720
    int n = idx % 120;
    float s = bias[n];
#pragma unroll 8
    for (int kb = 0; kb < 128; ++kb) s += partial[(size_t)kb * 30720 + idx];
    out[idx] = fmaxf(s, 0.f);
}

// fc2: features[256][84] = fc1out[256][120] @ w[84][120]^T + b
__global__ __launch_bounds__(256) void k_fc2(const float* __restrict__ h,
                                             const float* __restrict__ w,
                                             const float* __restrict__ bias,
                                             float* __restrict__ out) {
    int idx = blockIdx.x * 256 + threadIdx.x;   // 21504
    int n = idx % 84;
    int m = idx / 84;
    const float* hp = h + m * 120;
    const float* wp = w + n * 120;
    float s = bias[n];
#pragma unroll 4
    for (int k = 0; k < 120; ++k) s = fmaf(hp[k], wp[k], s);
    out[idx] = s;
}

// head: fc3 -> tanh-param layer -> sigmoid; also row norms of features
__global__ __launch_bounds__(256) void k_head(const float* __restrict__ f,
                                              const float* __restrict__ w3,
                                              const float* __restrict__ b3,
                                              const float* __restrict__ plw,
                                              const float* __restrict__ plb,
                                              const float* __restrict__ pls,
                                              const float* __restrict__ plbias,
                                              float* __restrict__ probs,
                                              float* __restrict__ norms) {
    int b = threadIdx.x;            // 0..255, single block
    const float* fp = f + b * 84;
    float nsq = 0.f, lg = b3[0];
#pragma unroll 4
    for (int k = 0; k < 84; ++k) {
        float v = fp[k];
        nsq = fmaf(v, v, nsq);
        lg  = fmaf(v, w3[k], lg);
    }
    float z = tanhf(lg * plw[0] + plb[0]) * pls[0] + plbias[0];
    probs[b] = 1.f / (1.f + expf(-z));
    norms[b] = sqrtf(nsq);
}

// graph: block i computes cosine-sim row i, adjacency, degree-weighted agg
__global__ __launch_bounds__(256) void k_graph(const float* __restrict__ f,
                                               const float* __restrict__ probs,
                                               const float* __restrict__ norms,
                                               float* __restrict__ out) {
    __shared__ float fi[84];
    __shared__ float sd[4], sv[4];
    int i = blockIdx.x;
    int j = threadIdx.x;
    if (j < 84) fi[j] = f[i * 84 + j];
    __syncthreads();
    const float* fj = f + j * 84;
    float dot = 0.f;
#pragma unroll 4
    for (int k = 0; k < 84; ++k) dot = fmaf(fi[k], fj[k], dot);
    float sim = dot / (norms[i] * norms[j] + 1e-12f);
    bool adj = (j != i) && (sim >= 0.0f);
    float d = adj ? 1.f : 0.f;
    float v = adj ? probs[j] : 0.f;
#pragma unroll
    for (int off = 32; off >= 1; off >>= 1) {
        d += __shfl_down(d, off);
        v += __shfl_down(v, off);
    }
    int wave = j >> 6, lane = j & 63;
    if (lane == 0) { sd[wave] = d; sv[wave] = v; }
    __syncthreads();
    if (j == 0) {
        float D = sd[0] + sd[1] + sd[2] + sd[3];
        float V = sv[0] + sv[1] + sv[2] + sv[3];
        float nm = (D > 0.f) ? (V / fmaxf(D, 1.f)) : 0.f;
        float agg = (probs[i] + nm) / (1.f + D);
        out[2 * i]     = agg;
        out[2 * i + 1] = 1.f - agg;
    }
}

extern "C" void kernel_launch(void* const* d_in, const int* in_sizes, int n_in,
                              void* d_out, int out_size, void* d_ws, size_t ws_size,
                              hipStream_t stream) {
    const float* x    = (const float*)d_in[0];
    const float* w1   = (const float*)d_in[1];
    const float* b1   = (const float*)d_in[2];
    const float* w2   = (const float*)d_in[3];
    const float* b2   = (const float*)d_in[4];
    const float* fw1  = (const float*)d_in[5];
    const float* fb1  = (const float*)d_in[6];
    const float* fw2  = (const float*)d_in[7];
    const float* fb2  = (const float*)d_in[8];
    const float* fw3  = (const float*)d_in[9];
    const float* fb3  = (const float*)d_in[10];
    const float* plw  = (const float*)d_in[11];
    const float* plb  = (const float*)d_in[12];
    const float* pls  = (const float*)d_in[13];
    const float* plbi = (const float*)d_in[14];
    float* out = (float*)d_out;

    float* ws = (float*)d_ws;
    float* p1       = ws;                          // 23,238,144 f
    float* p2       = p1 + 23238144;               // 14,288,640 f
    float* partial  = p2 + 14288640;               // 3,932,160 f
    float* fc1out   = partial + 3932160;           // 30,720 f
    float* features = fc1out + 30720;              // 21,504 f
    float* probs    = features + 21504;            // 256 f
    float* norms    = probs + 256;                 // 256 f

    k_c1p1<<<dim3(18, 256), 256, 0, stream>>>(x, w1, b1, p1);
    k_c2p2<<<dim3(9, 256), 256, 0, stream>>>(p1, w2, b2, p2);
    k_fc1<<<dim3(128, 2), 256, 0, stream>>>(p2, fw1, partial);
    k_fc1red<<<120, 256, 0, stream>>>(partial, fb1, fc1out);
    k_fc2<<<84, 256, 0, stream>>>(fc1out, fw2, fb2, features);
    k_head<<<1, 256, 0, stream>>>(features, fw3, fb3, plw, plb, pls, plbi,
                                  probs, norms);
    k_graph<<<256, 256, 0, stream>>>(features, probs, norms, out);
}

// Round 3
// 697.006 us; speedup vs baseline: 1.1942x; 1.1246x over previous
//
#include <hip/hip_runtime.h>
#include <math.h>

// ---------------------------------------------------------------------------
// Round 3: conflict-free phase-split conv+pool, b128 split-K fc1.
//   k_c1p1: conv1(5x5,s2,p1)+relu+pool(2x2,s1): x[256,3,250,250]->p1[256,6,123,123]
//   k_c2p2: conv2(3x3,s2,p1)+relu+pool(2x2,s1): p1 -> p2[256,15,61,61]
//   k_fc1 : split-K 256, 128x120 tile, BK=56, ds_read_b128 fragments
// ---------------------------------------------------------------------------

// conv1+pool1. Block: image b (blockIdx.y), 8 pooled rows (tile t=blockIdx.x, 16 tiles).
// 4 waves = 2 col-spans x 2 row-strips. lane -> conv col ow = 62*span + lane.
// Thread: 5 conv rows x 6 oc in regs; pool via reg-max + __shfl_down(+1).
// Input staged phase-split: xe[m]=col 2m, xo[m']=col 2m'-1 -> lane-stride-1 reads.
__global__ __launch_bounds__(256) void k_c1p1(const float* __restrict__ x,
                                              const float* __restrict__ w,
                                              const float* __restrict__ bias,
                                              float* __restrict__ p1) {
    __shared__ float xe[21][126];
    __shared__ float xo[21][126];

    const int t    = blockIdx.x;          // 0..15
    const int b    = blockIdx.y;          // 0..255
    const int tid  = threadIdx.x;
    const int lane = tid & 63;
    const int wv   = tid >> 6;            // 0..3
    const int s    = wv & 1;              // col span
    const int q    = wv >> 1;             // row strip
    const int ow   = 62 * s + lane;       // conv col
    const int owc  = min(ow, 123);        // clamp for LDS reads
    const int ihlo = 16 * t - 1;

    float acc[5][6];
#pragma unroll
    for (int j = 0; j < 5; ++j)
#pragma unroll
        for (int oc = 0; oc < 6; ++oc) acc[j][oc] = 0.f;

    const float* xb = x + (size_t)b * 3 * 62500;

    for (int ci = 0; ci < 3; ++ci) {
        __syncthreads();
        const float* xc = xb + (size_t)ci * 62500;
        // stage 21 rows x 250 cols, phase-split
#pragma unroll 1
        for (int sS = tid; sS < 21 * 256; sS += 256) {
            int r = sS >> 8;
            int c = sS & 255;
            if (c < 250) {
                int ih = ihlo + r;
                float v = (ih >= 0 && ih < 250) ? xc[(size_t)ih * 250 + c] : 0.f;
                if ((c & 1) == 0) xe[r][c >> 1] = v;
                else              xo[r][(c >> 1) + 1] = v;
            } else if (c == 254) {
                xo[r][0] = 0.f;   // col -1 pad
            }
        }
        __syncthreads();

        // u = relative input row within strip; input row lr = 8q+u serves all
        // (j,kh) with 2j+kh==u.  kw map: o0,v0,o1,v1,o2 <-> kw 0..4
#pragma unroll
        for (int u = 0; u <= 12; ++u) {
            const int lr = 8 * q + u;
            float v0 = xe[lr][owc];
            float v1 = xe[lr][owc + 1];
            float o0 = xo[lr][owc];
            float o1 = xo[lr][owc + 1];
            float o2 = xo[lr][owc + 2];
#pragma unroll
            for (int j = 0; j < 5; ++j) {
                int kh = u - 2 * j;
                if (kh >= 0 && kh < 5) {
#pragma unroll
                    for (int oc = 0; oc < 6; ++oc) {
                        const float* wp = w + ((oc * 3 + ci) * 5 + kh) * 5;
                        float a = acc[j][oc];
                        a = fmaf(o0, wp[0], a);
                        a = fmaf(v0, wp[1], a);
                        a = fmaf(o1, wp[2], a);
                        a = fmaf(v1, wp[3], a);
                        a = fmaf(o2, wp[4], a);
                        acc[j][oc] = a;
                    }
                }
            }
        }
    }

    // epilogue: bias+relu, vertical max, horizontal max via shuffle, store
    const int pw     = ow;                 // pooled col
    const int oh0    = 8 * t + 4 * q;
    const bool cok   = (lane < 63) && (pw < 123);
#pragma unroll
    for (int oc = 0; oc < 6; ++oc) {
        float bv = bias[oc];
        float r0 = fmaxf(acc[0][oc] + bv, 0.f);
        float r1 = fmaxf(acc[1][oc] + bv, 0.f);
        float r2 = fmaxf(acc[2][oc] + bv, 0.f);
        float r3 = fmaxf(acc[3][oc] + bv, 0.f);
        float r4 = fmaxf(acc[4][oc] + bv, 0.f);
        float vm0 = fmaxf(r0, r1), vm1 = fmaxf(r1, r2);
        float vm2 = fmaxf(r2, r3), vm3 = fmaxf(r3, r4);
        float p0 = fmaxf(vm0, __shfl_down(vm0, 1));
        float p1v = fmaxf(vm1, __shfl_down(vm1, 1));
        float p2v = fmaxf(vm2, __shfl_down(vm2, 1));
        float p3 = fmaxf(vm3, __shfl_down(vm3, 1));
        if (cok) {
            float* op = p1 + (((size_t)b * 6 + oc) * 123) * 123 + pw;
            if (oh0 + 0 < 123) op[(size_t)(oh0 + 0) * 123] = p0;
            if (oh0 + 1 < 123) op[(size_t)(oh0 + 1) * 123] = p1v;
            if (oh0 + 2 < 123) op[(size_t)(oh0 + 2) * 123] = p2v;
            if (oh0 + 3 < 123) op[(size_t)(oh0 + 3) * 123] = p3;
        }
    }
}

// conv2+pool2. Block: image b, 8 pooled rows (v=blockIdx.x, 8 tiles).
// 4 waves = 4 row strips; lane = conv col (62 used). Thread: 3 conv rows x 15 oc.
__global__ __launch_bounds__(256) void k_c2p2(const float* __restrict__ p1,
                                              const float* __restrict__ w,
                                              const float* __restrict__ bias,
                                              float* __restrict__ p2) {
    __shared__ float xe[19][63];
    __shared__ float xo[19][63];

    const int v    = blockIdx.x;          // 0..7
    const int b    = blockIdx.y;
    const int tid  = threadIdx.x;
    const int lane = tid & 63;
    const int q    = tid >> 6;            // 0..3
    const int ow   = lane;
    const int owc  = min(ow, 61);
    const int ihlo = 16 * v - 1;

    float acc[3][15];
#pragma unroll
    for (int j = 0; j < 3; ++j)
#pragma unroll
        for (int oc = 0; oc < 15; ++oc) acc[j][oc] = 0.f;

    const float* ib = p1 + (size_t)b * 6 * 15129;

    for (int ci = 0; ci < 6; ++ci) {
        __syncthreads();
        const float* xc = ib + (size_t)ci * 15129;
#pragma unroll 1
        for (int sS = tid; sS < 19 * 128; sS += 256) {
            int r = sS >> 7;
            int c = sS & 127;
            if (c < 123) {
                int ih = ihlo + r;
                float vv = (ih >= 0 && ih < 123) ? xc[(size_t)ih * 123 + c] : 0.f;
                if ((c & 1) == 0) xe[r][c >> 1] = vv;
                else              xo[r][(c >> 1) + 1] = vv;
            } else if (c == 124) {
                xo[r][0] = 0.f;
            } else if (c == 126) {
                xo[r][62] = 0.f;   // col 123 pad
            }
        }
        __syncthreads();

#pragma unroll
        for (int u = 0; u <= 6; ++u) {
            const int lr = 4 * q + u;
            float o0 = xo[lr][owc];
            float v0 = xe[lr][owc];
            float o1 = xo[lr][owc + 1];
#pragma unroll
            for (int j = 0; j < 3; ++j) {
                int kh = u - 2 * j;
                if (kh >= 0 && kh < 3) {
#pragma unroll
                    for (int oc = 0; oc < 15; ++oc) {
                        const float* wp = w + ((oc * 6 + ci) * 3 + kh) * 3;
                        float a = acc[j][oc];
                        a = fmaf(o0, wp[0], a);
                        a = fmaf(v0, wp[1], a);
                        a = fmaf(o1, wp[2], a);
                        acc[j][oc] = a;
                    }
                }
            }
        }
    }

    const int pw   = ow;
    const int oh0  = 8 * v + 2 * q;
    const bool cok = (lane < 61);
#pragma unroll
    for (int oc = 0; oc < 15; ++oc) {
        float bv = bias[oc];
        float r0 = fmaxf(acc[0][oc] + bv, 0.f);
        float r1 = fmaxf(acc[1][oc] + bv, 0.f);
        float r2 = fmaxf(acc[2][oc] + bv, 0.f);
        float vm0 = fmaxf(r0, r1), vm1 = fmaxf(r1, r2);
        float p0 = fmaxf(vm0, __shfl_down(vm0, 1));
        float p1v = fmaxf(vm1, __shfl_down(vm1, 1));
        if (cok) {
            float* op = p2 + (((size_t)b * 15 + oc) * 61) * 61 + pw;
            if (oh0 + 0 < 61) op[(size_t)(oh0 + 0) * 61] = p0;
            if (oh0 + 1 < 61) op[(size_t)(oh0 + 1) * 61] = p1v;
        }
    }
}

// fc1 split-K GEMM: A=p2[256][55815], B=fc1_w[120][55815].
// grid (256 kb, 2 mt), BK=56, LDS pitch 60 (16B-aligned rows) -> b128 reads.
__global__ __launch_bounds__(256) void k_fc1(const float* __restrict__ A,
                                             const float* __restrict__ B,
                                             float* __restrict__ partial) {
    __shared__ float As[128][60];
    __shared__ float Bs[128][60];
    const int K = 55815;
    int tid = threadIdx.x;
    int kb  = blockIdx.x;          // 0..255
    int m0  = blockIdx.y * 128;
    int mx  = tid >> 4;            // 0..15
    int nx  = tid & 15;            // 0..15

    float acc[8][8];
#pragma unroll
    for (int i = 0; i < 8; ++i)
#pragma unroll
        for (int j = 0; j < 8; ++j) acc[i][j] = 0.f;

    for (int ch = kb; ch < 997; ch += 256) {   // 997 = ceil(55815/56)
        int k0 = ch * 56;
        __syncthreads();
#pragma unroll 1
        for (int f = tid; f < 128 * 56; f += 256) {
            int m  = f / 56;
            int k2 = f - m * 56;
            int k  = k0 + k2;
            As[m][k2] = (k < K) ? A[(size_t)(m0 + m) * K + k] : 0.f;
            Bs[m][k2] = (k < K && m < 120) ? B[(size_t)m * K + k] : 0.f;
        }
        __syncthreads();
#pragma unroll 2
        for (int k4 = 0; k4 < 14; ++k4) {
            float4 af[8], bf[8];
#pragma unroll
            for (int i = 0; i < 8; ++i)
                af[i] = *(const float4*)&As[mx + 16 * i][k4 * 4];
#pragma unroll
            for (int j = 0; j < 8; ++j)
                bf[j] = *(const float4*)&Bs[nx + 16 * j][k4 * 4];
#pragma unroll
            for (int i = 0; i < 8; ++i)
#pragma unroll
                for (int j = 0; j < 8; ++j) {
                    acc[i][j] = fmaf(af[i].x, bf[j].x, acc[i][j]);
                    acc[i][j] = fmaf(af[i].y, bf[j].y, acc[i][j]);
                    acc[i][j] = fmaf(af[i].z, bf[j].z, acc[i][j]);
                    acc[i][j] = fmaf(af[i].w, bf[j].w, acc[i][j]);
                }
        }
    }

    float* pp = partial + (size_t)kb * 30720;
#pragma unroll
    for (int i = 0; i < 8; ++i) {
        int m = m0 + mx + 16 * i;
#pragma unroll
        for (int j = 0; j < 8; ++j) {
            int n = nx + 16 * j;
            if (n < 120) pp[m * 120 + n] = acc[i][j];
        }
    }
}

// reduce partials + bias + relu -> fc1out[256][120]
__global__ __launch_bounds__(256) void k_fc1red(const float* __restrict__ partial,
                                                const float* __restrict__ bias,
                                                float* __restrict__ out) {
    int idx = blockIdx.x * 256 + threadIdx.x;   // 30720
    int n = idx % 120;
    float s = bias[n];
#pragma unroll 8
    for (int kb = 0; kb < 256; ++kb) s += partial[(size_t)kb * 30720 + idx];
    out[idx] = fmaxf(s, 0.f);
}

// fc2: features[256][84] = fc1out[256][120] @ w[84][120]^T + b
__global__ __launch_bounds__(256) void k_fc2(const float* __restrict__ h,
                                             const float* __restrict__ w,
                                             const float* __restrict__ bias,
                                             float* __restrict__ out) {
    int idx = blockIdx.x * 256 + threadIdx.x;   // 21504
    int n = idx % 84;
    int m = idx / 84;
    const float* hp = h + m * 120;
    const float* wp = w + n * 120;
    float s = bias[n];
#pragma unroll 4
    for (int k = 0; k < 120; ++k) s = fmaf(hp[k], wp[k], s);
    out[idx] = s;
}

// head: fc3 -> tanh-param layer -> sigmoid; also row norms of features
__global__ __launch_bounds__(256) void k_head(const float* __restrict__ f,
                                              const float* __restrict__ w3,
                                              const float* __restrict__ b3,
                                              const float* __restrict__ plw,
                                              const float* __restrict__ plb,
                                              const float* __restrict__ pls,
                                              const float* __restrict__ plbias,
                                              float* __restrict__ probs,
                                              float* __restrict__ norms) {
    int b = threadIdx.x;            // 0..255, single block
    const float* fp = f + b * 84;
    float nsq = 0.f, lg = b3[0];
#pragma unroll 4
    for (int k = 0; k < 84; ++k) {
        float v = fp[k];
        nsq = fmaf(v, v, nsq);
        lg  = fmaf(v, w3[k], lg);
    }
    float z = tanhf(lg * plw[0] + plb[0]) * pls[0] + plbias[0];
    probs[b] = 1.f / (1.f + expf(-z));
    norms[b] = sqrtf(nsq);
}

// graph: block i computes cosine-sim row i, adjacency, degree-weighted agg
__global__ __launch_bounds__(256) void k_graph(const float* __restrict__ f,
                                               const float* __restrict__ probs,
                                               const float* __restrict__ norms,
                                               float* __restrict__ out) {
    __shared__ float fi[84];
    __shared__ float sd[4], sv[4];
    int i = blockIdx.x;
    int j = threadIdx.x;
    if (j < 84) fi[j] = f[i * 84 + j];
    __syncthreads();
    const float* fj = f + j * 84;
    float dot = 0.f;
#pragma unroll 4
    for (int k = 0; k < 84; ++k) dot = fmaf(fi[k], fj[k], dot);
    float sim = dot / (norms[i] * norms[j] + 1e-12f);
    bool adj = (j != i) && (sim >= 0.0f);
    float d = adj ? 1.f : 0.f;
    float v = adj ? probs[j] : 0.f;
#pragma unroll
    for (int off = 32; off >= 1; off >>= 1) {
        d += __shfl_down(d, off);
        v += __shfl_down(v, off);
    }
    int wave = j >> 6, lane = j & 63;
    if (lane == 0) { sd[wave] = d; sv[wave] = v; }
    __syncthreads();
    if (j == 0) {
        float D = sd[0] + sd[1] + sd[2] + sd[3];
        float V = sv[0] + sv[1] + sv[2] + sv[3];
        float nm = (D > 0.f) ? (V / fmaxf(D, 1.f)) : 0.f;
        float agg = (probs[i] + nm) / (1.f + D);
        out[2 * i]     = agg;
        out[2 * i + 1] = 1.f - agg;
    }
}

extern "C" void kernel_launch(void* const* d_in, const int* in_sizes, int n_in,
                              void* d_out, int out_size, void* d_ws, size_t ws_size,
                              hipStream_t stream) {
    const float* x    = (const float*)d_in[0];
    const float* w1   = (const float*)d_in[1];
    const float* b1   = (const float*)d_in[2];
    const float* w2   = (const float*)d_in[3];
    const float* b2   = (const float*)d_in[4];
    const float* fw1  = (const float*)d_in[5];
    const float* fb1  = (const float*)d_in[6];
    const float* fw2  = (const float*)d_in[7];
    const float* fb2  = (const float*)d_in[8];
    const float* fw3  = (const float*)d_in[9];
    const float* fb3  = (const float*)d_in[10];
    const float* plw  = (const float*)d_in[11];
    const float* plb  = (const float*)d_in[12];
    const float* pls  = (const float*)d_in[13];
    const float* plbi = (const float*)d_in[14];
    float* out = (float*)d_out;

    float* ws = (float*)d_ws;
    float* p1       = ws;                          // 23,238,144 f
    float* p2       = p1 + 23238144;               // 14,288,640 f
    float* partial  = p2 + 14288640;               // 7,864,320 f
    float* fc1out   = partial + 7864320;           // 30,720 f
    float* features = fc1out + 30720;              // 21,504 f
    float* probs    = features + 21504;            // 256 f
    float* norms    = probs + 256;                 // 256 f

    k_c1p1<<<dim3(16, 256), 256, 0, stream>>>(x, w1, b1, p1);
    k_c2p2<<<dim3(8, 256), 256, 0, stream>>>(p1, w2, b2, p2);
    k_fc1<<<dim3(256, 2), 256, 0, stream>>>(p2, fw1, partial);
    k_fc1red<<<120, 256, 0, stream>>>(partial, fb1, fc1out);
    k_fc2<<<84, 256, 0, stream>>>(fc1out, fw2, fb2, features);
    k_head<<<1, 256, 0, stream>>>(features, fw3, fb3, plw, plb, pls, plbi,
                                  probs, norms);
    k_graph<<<256, 256, 0, stream>>>(features, probs, norms, out);
}

// Round 4
// 639.591 us; speedup vs baseline: 1.3014x; 1.0898x over previous
//
#include <hip/hip_runtime.h>
#include <math.h>

// ---------------------------------------------------------------------------
// Round 4: batched-issue staging (deep MLP) everywhere.
//   k_c1p1: conv1(5x5,s2,p1)+relu+pool(2x2,s1): x[256,3,250,250]->p1[256,6,123,123]
//   k_c2p2: conv2(3x3,s2,p1)+relu+pool(2x2,s1): p1 -> p2[256,15,61,61]
//   k_fc1 : split-K 256, 128x120 tile, BK=64, batched loads, b128 fragments
// ---------------------------------------------------------------------------

// conv1+pool1. Block: image b (blockIdx.y), 8 pooled rows (t=blockIdx.x).
// 4 waves = 2 col-spans x 2 row-strips. lane -> conv col ow = 62*span + lane.
// Staging: float2, 11 independent loads/thread, clamped addresses.
__global__ __launch_bounds__(256) void k_c1p1(const float* __restrict__ x,
                                              const float* __restrict__ w,
                                              const float* __restrict__ bias,
                                              float* __restrict__ p1) {
    __shared__ float xe[21][126];
    __shared__ float xo[21][126];

    const int t    = blockIdx.x;          // 0..15
    const int b    = blockIdx.y;          // 0..255
    const int tid  = threadIdx.x;
    const int lane = tid & 63;
    const int wv   = tid >> 6;
    const int s    = wv & 1;              // col span
    const int q    = wv >> 1;             // row strip
    const int ow   = 62 * s + lane;
    const int owc  = min(ow, 123);
    const int ihlo = 16 * t - 1;

    const int sr = tid >> 7;              // 0..1 (staging row parity)
    const int sm = tid & 127;             // 0..127 (float2 index)
    const int smc = min(sm, 124);
    const bool smok = (sm < 125);

    float acc[5][6];
#pragma unroll
    for (int j = 0; j < 5; ++j)
#pragma unroll
        for (int oc = 0; oc < 6; ++oc) acc[j][oc] = 0.f;

    const float* xb = x + (size_t)b * 3 * 62500;

    for (int ci = 0; ci < 3; ++ci) {
        __syncthreads();
        const float* xc = xb + (size_t)ci * 62500;
        float2 vv[11];
#pragma unroll
        for (int i = 0; i < 11; ++i) {
            int r   = 2 * i + sr;
            int ih  = ihlo + r;
            bool ok = smok && (r < 21) && (ih >= 0) && (ih < 250);
            int ihc = min(max(ih, 0), 249);
            float2 raw = *(const float2*)(xc + (size_t)ihc * 250 + (smc << 1));
            vv[i].x = ok ? raw.x : 0.f;
            vv[i].y = ok ? raw.y : 0.f;
        }
#pragma unroll
        for (int i = 0; i < 11; ++i) {
            int r = 2 * i + sr;
            if (r < 21 && smok) {
                xe[r][sm] = vv[i].x;      // col 2*sm
                xo[r][sm + 1] = vv[i].y;  // col 2*sm+1
            }
        }
        if (tid < 21) xo[tid][0] = 0.f;   // col -1 pad
        __syncthreads();

        // input row lr = 8q+u serves all (j,kh) with 2j+kh==u
#pragma unroll
        for (int u = 0; u <= 12; ++u) {
            const int lr = 8 * q + u;
            float v0 = xe[lr][owc];
            float v1 = xe[lr][owc + 1];
            float o0 = xo[lr][owc];
            float o1 = xo[lr][owc + 1];
            float o2 = xo[lr][owc + 2];
#pragma unroll
            for (int j = 0; j < 5; ++j) {
                int kh = u - 2 * j;
                if (kh >= 0 && kh < 5) {
#pragma unroll
                    for (int oc = 0; oc < 6; ++oc) {
                        const float* wp = w + ((oc * 3 + ci) * 5 + kh) * 5;
                        float a = acc[j][oc];
                        a = fmaf(o0, wp[0], a);
                        a = fmaf(v0, wp[1], a);
                        a = fmaf(o1, wp[2], a);
                        a = fmaf(v1, wp[3], a);
                        a = fmaf(o2, wp[4], a);
                        acc[j][oc] = a;
                    }
                }
            }
        }
    }

    // epilogue: bias+relu, vertical max, horizontal max via shuffle, store
    const int pw   = ow;
    const int oh0  = 8 * t + 4 * q;
    const bool cok = (lane < 63) && (pw < 123);
#pragma unroll
    for (int oc = 0; oc < 6; ++oc) {
        float bv = bias[oc];
        float r0 = fmaxf(acc[0][oc] + bv, 0.f);
        float r1 = fmaxf(acc[1][oc] + bv, 0.f);
        float r2 = fmaxf(acc[2][oc] + bv, 0.f);
        float r3 = fmaxf(acc[3][oc] + bv, 0.f);
        float r4 = fmaxf(acc[4][oc] + bv, 0.f);
        float vm0 = fmaxf(r0, r1), vm1 = fmaxf(r1, r2);
        float vm2 = fmaxf(r2, r3), vm3 = fmaxf(r3, r4);
        float p0 = fmaxf(vm0, __shfl_down(vm0, 1));
        float p1v = fmaxf(vm1, __shfl_down(vm1, 1));
        float p2v = fmaxf(vm2, __shfl_down(vm2, 1));
        float p3 = fmaxf(vm3, __shfl_down(vm3, 1));
        if (cok) {
            float* op = p1 + (((size_t)b * 6 + oc) * 123) * 123 + pw;
            if (oh0 + 0 < 123) op[(size_t)(oh0 + 0) * 123] = p0;
            if (oh0 + 1 < 123) op[(size_t)(oh0 + 1) * 123] = p1v;
            if (oh0 + 2 < 123) op[(size_t)(oh0 + 2) * 123] = p2v;
            if (oh0 + 3 < 123) op[(size_t)(oh0 + 3) * 123] = p3;
        }
    }
}

// conv2+pool2. Block: image b, 8 pooled rows (v=blockIdx.x).
// 4 waves = 4 row strips; lane = conv col. Batched b32 staging.
__global__ __launch_bounds__(256) void k_c2p2(const float* __restrict__ p1,
                                              const float* __restrict__ w,
                                              const float* __restrict__ bias,
                                              float* __restrict__ p2) {
    __shared__ float xe[19][63];
    __shared__ float xo[19][63];

    const int v    = blockIdx.x;          // 0..7
    const int b    = blockIdx.y;
    const int tid  = threadIdx.x;
    const int lane = tid & 63;
    const int q    = tid >> 6;            // 0..3
    const int ow   = lane;
    const int owc  = min(ow, 61);
    const int ihlo = 16 * v - 1;

    const int sr = tid >> 7;              // 0..1
    const int sc = tid & 127;             // 0..127
    const int scc = min(sc, 122);
    const bool scok = (sc < 123);

    float acc[3][15];
#pragma unroll
    for (int j = 0; j < 3; ++j)
#pragma unroll
        for (int oc = 0; oc < 15; ++oc) acc[j][oc] = 0.f;

    const float* ib = p1 + (size_t)b * 6 * 15129;

    for (int ci = 0; ci < 6; ++ci) {
        __syncthreads();
        const float* xc = ib + (size_t)ci * 15129;
        float vv[10];
#pragma unroll
        for (int i = 0; i < 10; ++i) {
            int r   = 2 * i + sr;
            int ih  = ihlo + r;
            bool ok = scok && (r < 19) && (ih >= 0) && (ih < 123);
            int ihc = min(max(ih, 0), 122);
            float raw = xc[(size_t)ihc * 123 + scc];
            vv[i] = ok ? raw : 0.f;
        }
#pragma unroll
        for (int i = 0; i < 10; ++i) {
            int r = 2 * i + sr;
            if (r < 19 && scok) {
                if ((sc & 1) == 0) xe[r][sc >> 1] = vv[i];
                else               xo[r][(sc >> 1) + 1] = vv[i];
            }
        }
        if (tid < 19) { xo[tid][0] = 0.f; xo[tid][62] = 0.f; }
        __syncthreads();

#pragma unroll
        for (int u = 0; u <= 6; ++u) {
            const int lr = 4 * q + u;
            float o0 = xo[lr][owc];
            float v0 = xe[lr][owc];
            float o1 = xo[lr][owc + 1];
#pragma unroll
            for (int j = 0; j < 3; ++j) {
                int kh = u - 2 * j;
                if (kh >= 0 && kh < 3) {
#pragma unroll
                    for (int oc = 0; oc < 15; ++oc) {
                        const float* wp = w + ((oc * 6 + ci) * 3 + kh) * 3;
                        float a = acc[j][oc];
                        a = fmaf(o0, wp[0], a);
                        a = fmaf(v0, wp[1], a);
                        a = fmaf(o1, wp[2], a);
                        acc[j][oc] = a;
                    }
                }
            }
        }
    }

    const int pw   = ow;
    const int oh0  = 8 * v + 2 * q;
    const bool cok = (lane < 61);
#pragma unroll
    for (int oc = 0; oc < 15; ++oc) {
        float bv = bias[oc];
        float r0 = fmaxf(acc[0][oc] + bv, 0.f);
        float r1 = fmaxf(acc[1][oc] + bv, 0.f);
        float r2 = fmaxf(acc[2][oc] + bv, 0.f);
        float vm0 = fmaxf(r0, r1), vm1 = fmaxf(r1, r2);
        float p0 = fmaxf(vm0, __shfl_down(vm0, 1));
        float p1v = fmaxf(vm1, __shfl_down(vm1, 1));
        if (cok) {
            float* op = p2 + (((size_t)b * 15 + oc) * 61) * 61 + pw;
            if (oh0 + 0 < 61) op[(size_t)(oh0 + 0) * 61] = p0;
            if (oh0 + 1 < 61) op[(size_t)(oh0 + 1) * 61] = p1v;
        }
    }
}

// fc1 split-K GEMM: A=p2[256][55815], B=fc1_w[120][55815].
// grid (256 kb, 2 mt), BK=64, batched staging (8 A + 8 B loads in flight),
// LDS pitch 64, ds_read_b128 fragments.
__global__ __launch_bounds__(256) void k_fc1(const float* __restrict__ A,
                                             const float* __restrict__ B,
                                             float* __restrict__ partial) {
    __shared__ float As[128][64];
    __shared__ float Bs[128][64];
    const int K = 55815;
    int tid = threadIdx.x;
    int kb  = blockIdx.x;          // 0..255
    int m0  = blockIdx.y * 128;
    int mx  = tid >> 4;            // 0..15
    int nx  = tid & 15;            // 0..15
    int kl  = tid & 63;            // staging col
    int mb  = tid >> 6;            // staging row base

    // rows 120..127 of Bs are never staged: zero once (never overwritten)
    Bs[120 + mb][kl] = 0.f;
    Bs[124 + mb][kl] = 0.f;

    float acc[8][8];
#pragma unroll
    for (int i = 0; i < 8; ++i)
#pragma unroll
        for (int j = 0; j < 8; ++j) acc[i][j] = 0.f;

    for (int ch = kb; ch < 873; ch += 256) {   // 873 = ceil(55815/64)
        int k    = ch * 64 + kl;
        bool kok = (k < K);
        int kc   = kok ? k : K - 1;
        __syncthreads();
#pragma unroll
        for (int batch = 0; batch < 4; ++batch) {
            float va[8], vb[8];
#pragma unroll
            for (int u = 0; u < 8; ++u) {
                int m = mb + 4 * (batch * 8 + u);
                va[u] = A[(size_t)(m0 + m) * K + kc];
            }
#pragma unroll
            for (int u = 0; u < 8; ++u) {
                if (batch < 3 || u < 6) {      // B rows 0..119 only
                    int m = mb + 4 * (batch * 8 + u);
                    vb[u] = B[(size_t)m * K + kc];
                }
            }
#pragma unroll
            for (int u = 0; u < 8; ++u) {
                int m = mb + 4 * (batch * 8 + u);
                As[m][kl] = kok ? va[u] : 0.f;
            }
#pragma unroll
            for (int u = 0; u < 8; ++u) {
                if (batch < 3 || u < 6) {
                    int m = mb + 4 * (batch * 8 + u);
                    Bs[m][kl] = kok ? vb[u] : 0.f;
                }
            }
        }
        __syncthreads();
#pragma unroll 2
        for (int k4 = 0; k4 < 16; ++k4) {
            float4 af[8], bf[8];
#pragma unroll
            for (int i = 0; i < 8; ++i)
                af[i] = *(const float4*)&As[mx + 16 * i][k4 * 4];
#pragma unroll
            for (int j = 0; j < 8; ++j)
                bf[j] = *(const float4*)&Bs[nx + 16 * j][k4 * 4];
#pragma unroll
            for (int i = 0; i < 8; ++i)
#pragma unroll
                for (int j = 0; j < 8; ++j) {
                    acc[i][j] = fmaf(af[i].x, bf[j].x, acc[i][j]);
                    acc[i][j] = fmaf(af[i].y, bf[j].y, acc[i][j]);
                    acc[i][j] = fmaf(af[i].z, bf[j].z, acc[i][j]);
                    acc[i][j] = fmaf(af[i].w, bf[j].w, acc[i][j]);
                }
        }
    }

    float* pp = partial + (size_t)kb * 30720;
#pragma unroll
    for (int i = 0; i < 8; ++i) {
        int m = m0 + mx + 16 * i;
#pragma unroll
        for (int j = 0; j < 8; ++j) {
            int n = nx + 16 * j;
            if (n < 120) pp[m * 120 + n] = acc[i][j];
        }
    }
}

// reduce partials + bias + relu -> fc1out[256][120]
__global__ __launch_bounds__(256) void k_fc1red(const float* __restrict__ partial,
                                                const float* __restrict__ bias,
                                                float* __restrict__ out) {
    int idx = blockIdx.x * 256 + threadIdx.x;   // 30720
    int n = idx % 120;
    float s = bias[n];
#pragma unroll 8
    for (int kb = 0; kb < 256; ++kb) s += partial[(size_t)kb * 30720 + idx];
    out[idx] = fmaxf(s, 0.f);
}

// fc2: features[256][84] = fc1out[256][120] @ w[84][120]^T + b
__global__ __launch_bounds__(256) void k_fc2(const float* __restrict__ h,
                                             const float* __restrict__ w,
                                             const float* __restrict__ bias,
                                             float* __restrict__ out) {
    int idx = blockIdx.x * 256 + threadIdx.x;   // 21504
    int n = idx % 84;
    int m = idx / 84;
    const float* hp = h + m * 120;
    const float* wp = w + n * 120;
    float s = bias[n];
#pragma unroll 4
    for (int k = 0; k < 120; ++k) s = fmaf(hp[k], wp[k], s);
    out[idx] = s;
}

// head: fc3 -> tanh-param layer -> sigmoid; also row norms of features
__global__ __launch_bounds__(256) void k_head(const float* __restrict__ f,
                                              const float* __restrict__ w3,
                                              const float* __restrict__ b3,
                                              const float* __restrict__ plw,
                                              const float* __restrict__ plb,
                                              const float* __restrict__ pls,
                                              const float* __restrict__ plbias,
                                              float* __restrict__ probs,
                                              float* __restrict__ norms) {
    int b = threadIdx.x;            // 0..255, single block
    const float* fp = f + b * 84;
    float nsq = 0.f, lg = b3[0];
#pragma unroll 4
    for (int k = 0; k < 84; ++k) {
        float v = fp[k];
        nsq = fmaf(v, v, nsq);
        lg  = fmaf(v, w3[k], lg);
    }
    float z = tanhf(lg * plw[0] + plb[0]) * pls[0] + plbias[0];
    probs[b] = 1.f / (1.f + expf(-z));
    norms[b] = sqrtf(nsq);
}

// graph: block i computes cosine-sim row i, adjacency, degree-weighted agg
__global__ __launch_bounds__(256) void k_graph(const float* __restrict__ f,
                                               const float* __restrict__ probs,
                                               const float* __restrict__ norms,
                                               float* __restrict__ out) {
    __shared__ float fi[84];
    __shared__ float sd[4], sv[4];
    int i = blockIdx.x;
    int j = threadIdx.x;
    if (j < 84) fi[j] = f[i * 84 + j];
    __syncthreads();
    const float* fj = f + j * 84;
    float dot = 0.f;
#pragma unroll 4
    for (int k = 0; k < 84; ++k) dot = fmaf(fi[k], fj[k], dot);
    float sim = dot / (norms[i] * norms[j] + 1e-12f);
    bool adj = (j != i) && (sim >= 0.0f);
    float d = adj ? 1.f : 0.f;
    float v = adj ? probs[j] : 0.f;
#pragma unroll
    for (int off = 32; off >= 1; off >>= 1) {
        d += __shfl_down(d, off);
        v += __shfl_down(v, off);
    }
    int wave = j >> 6, lane = j & 63;
    if (lane == 0) { sd[wave] = d; sv[wave] = v; }
    __syncthreads();
    if (j == 0) {
        float D = sd[0] + sd[1] + sd[2] + sd[3];
        float V = sv[0] + sv[1] + sv[2] + sv[3];
        float nm = (D > 0.f) ? (V / fmaxf(D, 1.f)) : 0.f;
        float agg = (probs[i] + nm) / (1.f + D);
        out[2 * i]     = agg;
        out[2 * i + 1] = 1.f - agg;
    }
}

extern "C" void kernel_launch(void* const* d_in, const int* in_sizes, int n_in,
                              void* d_out, int out_size, void* d_ws, size_t ws_size,
                              hipStream_t stream) {
    const float* x    = (const float*)d_in[0];
    const float* w1   = (const float*)d_in[1];
    const float* b1   = (const float*)d_in[2];
    const float* w2   = (const float*)d_in[3];
    const float* b2   = (const float*)d_in[4];
    const float* fw1  = (const float*)d_in[5];
    const float* fb1  = (const float*)d_in[6];
    const float* fw2  = (const float*)d_in[7];
    const float* fb2  = (const float*)d_in[8];
    const float* fw3  = (const float*)d_in[9];
    const float* fb3  = (const float*)d_in[10];
    const float* plw  = (const float*)d_in[11];
    const float* plb  = (const float*)d_in[12];
    const float* pls  = (const float*)d_in[13];
    const float* plbi = (const float*)d_in[14];
    float* out = (float*)d_out;

    float* ws = (float*)d_ws;
    float* p1       = ws;                          // 23,238,144 f
    float* p2       = p1 + 23238144;               // 14,288,640 f
    float* partial  = p2 + 14288640;               // 7,864,320 f
    float* fc1out   = partial + 7864320;           // 30,720 f
    float* features = fc1out + 30720;              // 21,504 f
    float* probs    = features + 21504;            // 256 f
    float* norms    = probs + 256;                 // 256 f

    k_c1p1<<<dim3(16, 256), 256, 0, stream>>>(x, w1, b1, p1);
    k_c2p2<<<dim3(8, 256), 256, 0, stream>>>(p1, w2, b2, p2);
    k_fc1<<<dim3(256, 2), 256, 0, stream>>>(p2, fw1, partial);
    k_fc1red<<<120, 256, 0, stream>>>(partial, fb1, fc1out);
    k_fc2<<<84, 256, 0, stream>>>(fc1out, fw2, fb2, features);
    k_head<<<1, 256, 0, stream>>>(features, fw3, fb3, plw, plb, pls, plbi,
                                  probs, norms);
    k_graph<<<256, 256, 0, stream>>>(features, probs, norms, out);
}

// Round 5
// 585.357 us; speedup vs baseline: 1.4220x; 1.0927x over previous
//
#include <hip/hip_runtime.h>
#include <math.h>

// ---------------------------------------------------------------------------
// Round 5: single-array LDS staging (2-way stride-2 reads are free on
// wave64/32-bank), kh-outer conv loops with per-(ci,kh) weight hoisting into
// uniform (SGPR) arrays so each weight is loaded once per ci.
// ---------------------------------------------------------------------------

// conv1+pool1. Block: image b (blockIdx.y), 8 pooled rows (t=blockIdx.x).
// 4 waves = 2 col-spans x 2 row-strips. lane -> conv col ow = 62*span + lane.
// LDS: xs[r][c] holds input col g=c-1 (col 0 = left pad).
__global__ __launch_bounds__(256) void k_c1p1(const float* __restrict__ x,
                                              const float* __restrict__ w,
                                              const float* __restrict__ bias,
                                              float* __restrict__ p1) {
    __shared__ float xs[21][256];

    const int t    = blockIdx.x;          // 0..15
    const int b    = blockIdx.y;          // 0..255
    const int tid  = threadIdx.x;
    const int lane = tid & 63;
    const int wv   = tid >> 6;
    const int s    = wv & 1;              // col span
    const int q    = wv >> 1;             // row strip
    const int ow   = 62 * s + lane;
    const int owc  = min(ow, 123);
    const int ihlo = 16 * t - 1;

    const int sr  = tid >> 7;             // 0..1 staging row parity
    const int sm  = tid & 127;            // float2 index
    const int smc = min(sm, 124);
    const bool smok = (sm < 125);

    float acc[5][6];
#pragma unroll
    for (int j = 0; j < 5; ++j)
#pragma unroll
        for (int oc = 0; oc < 6; ++oc) acc[j][oc] = 0.f;

    const float* xb = x + (size_t)b * 3 * 62500;

#pragma unroll 1
    for (int ci = 0; ci < 3; ++ci) {
        __syncthreads();
        const float* xc = xb + (size_t)ci * 62500;
        float2 vv[11];
#pragma unroll
        for (int i = 0; i < 11; ++i) {
            int r   = 2 * i + sr;
            int ih  = ihlo + r;
            bool ok = smok && (r < 21) && (ih >= 0) && (ih < 250);
            int ihc = min(max(ih, 0), 249);
            float2 raw = *(const float2*)(xc + (size_t)ihc * 250 + (smc << 1));
            vv[i].x = ok ? raw.x : 0.f;
            vv[i].y = ok ? raw.y : 0.f;
        }
#pragma unroll
        for (int i = 0; i < 11; ++i) {
            int r = 2 * i + sr;
            if (r < 21 && smok) {
                xs[r][2 * sm + 1] = vv[i].x;   // global col 2sm
                xs[r][2 * sm + 2] = vv[i].y;   // global col 2sm+1
            }
        }
        if (tid < 21) xs[tid][0] = 0.f;        // col -1 pad
        __syncthreads();

        // kh-outer: hoist 30 weights (uniform -> SGPRs), then 5 rows x 6 oc
#pragma unroll
        for (int kh = 0; kh < 5; ++kh) {
            float wk[6][5];
#pragma unroll
            for (int oc = 0; oc < 6; ++oc)
#pragma unroll
                for (int kw = 0; kw < 5; ++kw)
                    wk[oc][kw] = w[((oc * 3 + ci) * 5 + kh) * 5 + kw];
#pragma unroll
            for (int j = 0; j < 5; ++j) {
                const int lr = 8 * q + 2 * j + kh;
                float r0 = xs[lr][2 * owc + 0];   // g = 2ow-1
                float r1 = xs[lr][2 * owc + 1];
                float r2 = xs[lr][2 * owc + 2];
                float r3 = xs[lr][2 * owc + 3];
                float r4 = xs[lr][2 * owc + 4];   // g = 2ow+3
#pragma unroll
                for (int oc = 0; oc < 6; ++oc) {
                    float a = acc[j][oc];
                    a = fmaf(r0, wk[oc][0], a);
                    a = fmaf(r1, wk[oc][1], a);
                    a = fmaf(r2, wk[oc][2], a);
                    a = fmaf(r3, wk[oc][3], a);
                    a = fmaf(r4, wk[oc][4], a);
                    acc[j][oc] = a;
                }
            }
        }
    }

    // epilogue: bias+relu, vertical max, horizontal max via shuffle, store
    const int pw   = ow;
    const int oh0  = 8 * t + 4 * q;
    const bool cok = (lane < 63) && (pw < 123);
#pragma unroll
    for (int oc = 0; oc < 6; ++oc) {
        float bv = bias[oc];
        float r0 = fmaxf(acc[0][oc] + bv, 0.f);
        float r1 = fmaxf(acc[1][oc] + bv, 0.f);
        float r2 = fmaxf(acc[2][oc] + bv, 0.f);
        float r3 = fmaxf(acc[3][oc] + bv, 0.f);
        float r4 = fmaxf(acc[4][oc] + bv, 0.f);
        float vm0 = fmaxf(r0, r1), vm1 = fmaxf(r1, r2);
        float vm2 = fmaxf(r2, r3), vm3 = fmaxf(r3, r4);
        float p0 = fmaxf(vm0, __shfl_down(vm0, 1));
        float p1v = fmaxf(vm1, __shfl_down(vm1, 1));
        float p2v = fmaxf(vm2, __shfl_down(vm2, 1));
        float p3 = fmaxf(vm3, __shfl_down(vm3, 1));
        if (cok) {
            float* op = p1 + (((size_t)b * 6 + oc) * 123) * 123 + pw;
            if (oh0 + 0 < 123) op[(size_t)(oh0 + 0) * 123] = p0;
            if (oh0 + 1 < 123) op[(size_t)(oh0 + 1) * 123] = p1v;
            if (oh0 + 2 < 123) op[(size_t)(oh0 + 2) * 123] = p2v;
            if (oh0 + 3 < 123) op[(size_t)(oh0 + 3) * 123] = p3;
        }
    }
}

// conv2+pool2. Block: image b, 8 pooled rows (v=blockIdx.x).
// 4 waves = 4 row strips; lane = conv col. Single LDS array, kh-outer weights.
__global__ __launch_bounds__(256) void k_c2p2(const float* __restrict__ p1,
                                              const float* __restrict__ w,
                                              const float* __restrict__ bias,
                                              float* __restrict__ p2) {
    __shared__ float xs[19][128];

    const int v    = blockIdx.x;          // 0..7
    const int b    = blockIdx.y;
    const int tid  = threadIdx.x;
    const int lane = tid & 63;
    const int q    = tid >> 6;            // 0..3
    const int ow   = lane;
    const int owc  = min(ow, 61);
    const int ihlo = 16 * v - 1;

    const int sr  = tid >> 7;             // 0..1
    const int sc  = tid & 127;            // 0..127
    const int scc = min(sc, 122);
    const bool scok = (sc < 123);

    float acc[3][15];
#pragma unroll
    for (int j = 0; j < 3; ++j)
#pragma unroll
        for (int oc = 0; oc < 15; ++oc) acc[j][oc] = 0.f;

    const float* ib = p1 + (size_t)b * 6 * 15129;

#pragma unroll 1
    for (int ci = 0; ci < 6; ++ci) {
        __syncthreads();
        const float* xc = ib + (size_t)ci * 15129;
        float vv[10];
#pragma unroll
        for (int i = 0; i < 10; ++i) {
            int r   = 2 * i + sr;
            int ih  = ihlo + r;
            bool ok = scok && (r < 19) && (ih >= 0) && (ih < 123);
            int ihc = min(max(ih, 0), 122);
            float raw = xc[(size_t)ihc * 123 + scc];
            vv[i] = ok ? raw : 0.f;
        }
#pragma unroll
        for (int i = 0; i < 10; ++i) {
            int r = 2 * i + sr;
            if (r < 19 && scok) xs[r][sc + 1] = vv[i];   // global col sc
        }
        if (tid < 19) { xs[tid][0] = 0.f; xs[tid][124] = 0.f; }
        __syncthreads();

#pragma unroll
        for (int kh = 0; kh < 3; ++kh) {
            float wk[15][3];
#pragma unroll
            for (int oc = 0; oc < 15; ++oc)
#pragma unroll
                for (int kw = 0; kw < 3; ++kw)
                    wk[oc][kw] = w[((oc * 6 + ci) * 3 + kh) * 3 + kw];
#pragma unroll
            for (int j = 0; j < 3; ++j) {
                const int lr = 4 * q + 2 * j + kh;
                float r0 = xs[lr][2 * owc + 0];   // g = 2ow-1
                float r1 = xs[lr][2 * owc + 1];
                float r2 = xs[lr][2 * owc + 2];   // g = 2ow+1
#pragma unroll
                for (int oc = 0; oc < 15; ++oc) {
                    float a = acc[j][oc];
                    a = fmaf(r0, wk[oc][0], a);
                    a = fmaf(r1, wk[oc][1], a);
                    a = fmaf(r2, wk[oc][2], a);
                    acc[j][oc] = a;
                }
            }
        }
    }

    const int pw   = ow;
    const int oh0  = 8 * v + 2 * q;
    const bool cok = (lane < 61);
#pragma unroll
    for (int oc = 0; oc < 15; ++oc) {
        float bv = bias[oc];
        float r0 = fmaxf(acc[0][oc] + bv, 0.f);
        float r1 = fmaxf(acc[1][oc] + bv, 0.f);
        float r2 = fmaxf(acc[2][oc] + bv, 0.f);
        float vm0 = fmaxf(r0, r1), vm1 = fmaxf(r1, r2);
        float p0 = fmaxf(vm0, __shfl_down(vm0, 1));
        float p1v = fmaxf(vm1, __shfl_down(vm1, 1));
        if (cok) {
            float* op = p2 + (((size_t)b * 15 + oc) * 61) * 61 + pw;
            if (oh0 + 0 < 61) op[(size_t)(oh0 + 0) * 61] = p0;
            if (oh0 + 1 < 61) op[(size_t)(oh0 + 1) * 61] = p1v;
        }
    }
}

// fc1 split-K GEMM: A=p2[256][55815], B=fc1_w[120][55815].
// grid (256 kb, 2 mt), BK=64, batched staging, b128 LDS fragments.
__global__ __launch_bounds__(256) void k_fc1(const float* __restrict__ A,
                                             const float* __restrict__ B,
                                             float* __restrict__ partial) {
    __shared__ float As[128][64];
    __shared__ float Bs[128][64];
    const int K = 55815;
    int tid = threadIdx.x;
    int kb  = blockIdx.x;          // 0..255
    int m0  = blockIdx.y * 128;
    int mx  = tid >> 4;            // 0..15
    int nx  = tid & 15;            // 0..15
    int kl  = tid & 63;            // staging col
    int mb  = tid >> 6;            // staging row base

    Bs[120 + mb][kl] = 0.f;
    Bs[124 + mb][kl] = 0.f;

    float acc[8][8];
#pragma unroll
    for (int i = 0; i < 8; ++i)
#pragma unroll
        for (int j = 0; j < 8; ++j) acc[i][j] = 0.f;

    for (int ch = kb; ch < 873; ch += 256) {   // 873 = ceil(55815/64)
        int k    = ch * 64 + kl;
        bool kok = (k < K);
        int kc   = kok ? k : K - 1;
        __syncthreads();
#pragma unroll
        for (int batch = 0; batch < 4; ++batch) {
            float va[8], vb[8];
#pragma unroll
            for (int u = 0; u < 8; ++u) {
                int m = mb + 4 * (batch * 8 + u);
                va[u] = A[(size_t)(m0 + m) * K + kc];
            }
#pragma unroll
            for (int u = 0; u < 8; ++u) {
                if (batch < 3 || u < 6) {      // B rows 0..119 only
                    int m = mb + 4 * (batch * 8 + u);
                    vb[u] = B[(size_t)m * K + kc];
                }
            }
#pragma unroll
            for (int u = 0; u < 8; ++u) {
                int m = mb + 4 * (batch * 8 + u);
                As[m][kl] = kok ? va[u] : 0.f;
            }
#pragma unroll
            for (int u = 0; u < 8; ++u) {
                if (batch < 3 || u < 6) {
                    int m = mb + 4 * (batch * 8 + u);
                    Bs[m][kl] = kok ? vb[u] : 0.f;
                }
            }
        }
        __syncthreads();
#pragma unroll 2
        for (int k4 = 0; k4 < 16; ++k4) {
            float4 af[8], bf[8];
#pragma unroll
            for (int i = 0; i < 8; ++i)
                af[i] = *(const float4*)&As[mx + 16 * i][k4 * 4];
#pragma unroll
            for (int j = 0; j < 8; ++j)
                bf[j] = *(const float4*)&Bs[nx + 16 * j][k4 * 4];
#pragma unroll
            for (int i = 0; i < 8; ++i)
#pragma unroll
                for (int j = 0; j < 8; ++j) {
                    acc[i][j] = fmaf(af[i].x, bf[j].x, acc[i][j]);
                    acc[i][j] = fmaf(af[i].y, bf[j].y, acc[i][j]);
                    acc[i][j] = fmaf(af[i].z, bf[j].z, acc[i][j]);
                    acc[i][j] = fmaf(af[i].w, bf[j].w, acc[i][j]);
                }
        }
    }

    float* pp = partial + (size_t)kb * 30720;
#pragma unroll
    for (int i = 0; i < 8; ++i) {
        int m = m0 + mx + 16 * i;
#pragma unroll
        for (int j = 0; j < 8; ++j) {
            int n = nx + 16 * j;
            if (n < 120) pp[m * 120 + n] = acc[i][j];
        }
    }
}

// reduce partials + bias + relu -> fc1out[256][120]
__global__ __launch_bounds__(256) void k_fc1red(const float* __restrict__ partial,
                                                const float* __restrict__ bias,
                                                float* __restrict__ out) {
    int idx = blockIdx.x * 256 + threadIdx.x;   // 30720
    int n = idx % 120;
    float s = bias[n];
#pragma unroll 8
    for (int kb = 0; kb < 256; ++kb) s += partial[(size_t)kb * 30720 + idx];
    out[idx] = fmaxf(s, 0.f);
}

// fc2: features[256][84] = fc1out[256][120] @ w[84][120]^T + b
__global__ __launch_bounds__(256) void k_fc2(const float* __restrict__ h,
                                             const float* __restrict__ w,
                                             const float* __restrict__ bias,
                                             float* __restrict__ out) {
    int idx = blockIdx.x * 256 + threadIdx.x;   // 21504
    int n = idx % 84;
    int m = idx / 84;
    const float* hp = h + m * 120;
    const float* wp = w + n * 120;
    float s = bias[n];
#pragma unroll 4
    for (int k = 0; k < 120; ++k) s = fmaf(hp[k], wp[k], s);
    out[idx] = s;
}

// head: fc3 -> tanh-param layer -> sigmoid; also row norms of features
__global__ __launch_bounds__(256) void k_head(const float* __restrict__ f,
                                              const float* __restrict__ w3,
                                              const float* __restrict__ b3,
                                              const float* __restrict__ plw,
                                              const float* __restrict__ plb,
                                              const float* __restrict__ pls,
                                              const float* __restrict__ plbias,
                                              float* __restrict__ probs,
                                              float* __restrict__ norms) {
    int b = threadIdx.x;            // 0..255, single block
    const float* fp = f + b * 84;
    float nsq = 0.f, lg = b3[0];
#pragma unroll 4
    for (int k = 0; k < 84; ++k) {
        float v = fp[k];
        nsq = fmaf(v, v, nsq);
        lg  = fmaf(v, w3[k], lg);
    }
    float z = tanhf(lg * plw[0] + plb[0]) * pls[0] + plbias[0];
    probs[b] = 1.f / (1.f + expf(-z));
    norms[b] = sqrtf(nsq);
}

// graph: block i computes cosine-sim row i, adjacency, degree-weighted agg
__global__ __launch_bounds__(256) void k_graph(const float* __restrict__ f,
                                               const float* __restrict__ probs,
                                               const float* __restrict__ norms,
                                               float* __restrict__ out) {
    __shared__ float fi[84];
    __shared__ float sd[4], sv[4];
    int i = blockIdx.x;
    int j = threadIdx.x;
    if (j < 84) fi[j] = f[i * 84 + j];
    __syncthreads();
    const float* fj = f + j * 84;
    float dot = 0.f;
#pragma unroll 4
    for (int k = 0; k < 84; ++k) dot = fmaf(fi[k], fj[k], dot);
    float sim = dot / (norms[i] * norms[j] + 1e-12f);
    bool adj = (j != i) && (sim >= 0.0f);
    float d = adj ? 1.f : 0.f;
    float v = adj ? probs[j] : 0.f;
#pragma unroll
    for (int off = 32; off >= 1; off >>= 1) {
        d += __shfl_down(d, off);
        v += __shfl_down(v, off);
    }
    int wave = j >> 6, lane = j & 63;
    if (lane == 0) { sd[wave] = d; sv[wave] = v; }
    __syncthreads();
    if (j == 0) {
        float D = sd[0] + sd[1] + sd[2] + sd[3];
        float V = sv[0] + sv[1] + sv[2] + sv[3];
        float nm = (D > 0.f) ? (V / fmaxf(D, 1.f)) : 0.f;
        float agg = (probs[i] + nm) / (1.f + D);
        out[2 * i]     = agg;
        out[2 * i + 1] = 1.f - agg;
    }
}

extern "C" void kernel_launch(void* const* d_in, const int* in_sizes, int n_in,
                              void* d_out, int out_size, void* d_ws, size_t ws_size,
                              hipStream_t stream) {
    const float* x    = (const float*)d_in[0];
    const float* w1   = (const float*)d_in[1];
    const float* b1   = (const float*)d_in[2];
    const float* w2   = (const float*)d_in[3];
    const float* b2   = (const float*)d_in[4];
    const float* fw1  = (const float*)d_in[5];
    const float* fb1  = (const float*)d_in[6];
    const float* fw2  = (const float*)d_in[7];
    const float* fb2  = (const float*)d_in[8];
    const float* fw3  = (const float*)d_in[9];
    const float* fb3  = (const float*)d_in[10];
    const float* plw  = (const float*)d_in[11];
    const float* plb  = (const float*)d_in[12];
    const float* pls  = (const float*)d_in[13];
    const float* plbi = (const float*)d_in[14];
    float* out = (float*)d_out;

    float* ws = (float*)d_ws;
    float* p1       = ws;                          // 23,238,144 f
    float* p2       = p1 + 23238144;               // 14,288,640 f
    float* partial  = p2 + 14288640;               // 7,864,320 f
    float* fc1out   = partial + 7864320;           // 30,720 f
    float* features = fc1out + 30720;              // 21,504 f
    float* probs    = features + 21504;            // 256 f
    float* norms    = probs + 256;                 // 256 f

    k_c1p1<<<dim3(16, 256), 256, 0, stream>>>(x, w1, b1, p1);
    k_c2p2<<<dim3(8, 256), 256, 0, stream>>>(p1, w2, b2, p2);
    k_fc1<<<dim3(256, 2), 256, 0, stream>>>(p2, fw1, partial);
    k_fc1red<<<120, 256, 0, stream>>>(partial, fb1, fc1out);
    k_fc2<<<84, 256, 0, stream>>>(fc1out, fw2, fb2, features);
    k_head<<<1, 256, 0, stream>>>(features, fw3, fb3, plw, plb, pls, plbi,
                                  probs, norms);
    k_graph<<<256, 256, 0, stream>>>(features, probs, norms, out);
}